// Round 6
// baseline (356.318 us; speedup 1.0000x reference)
//
#include <hip/hip_runtime.h>
#include <hip/hip_bf16.h>
#include <math.h>

namespace {
constexpr int kDModel = 2048;
constexpr int kHeads  = 32;
constexpr int kState  = 64;
constexpr int kP      = 64;    // head dim = D_MODEL / N_HEADS
constexpr int kChunk  = 256;
constexpr int kNChunk = 16;    // SEQLEN / CHUNK
constexpr int kBatch  = 2;
constexpr int kSeq    = 4096;
constexpr int kM      = kBatch * kSeq;  // 8192 rows
}

typedef __bf16 bf16_t;
typedef __attribute__((ext_vector_type(8))) __bf16 bf16x8;
typedef __attribute__((ext_vector_type(4))) __bf16 bf16x4;
typedef __attribute__((ext_vector_type(4))) float f32x4;

__device__ __forceinline__ void gload_lds16(const void* g, void* l) {
    __builtin_amdgcn_global_load_lds(
        (const __attribute__((address_space(1))) void*)g,
        (__attribute__((address_space(3))) void*)l,
        16, 0, 0);
}

// ---------------------------------------------------------------------------
// B/C/dt projection GEMM v2: reads fp32 x DIRECTLY (no xb pre-cvt), BN=160
// (no pad waste; old version computed 256 cols, 160 useful). BM=32, grid 256
// blocks, 4 waves (2x2: wave 16 x 80). A staged by registers with fp32->bf16
// cvt (32x32 tile, 1 float4/thread); W staged via global_load_lds (160x32).
// ---------------------------------------------------------------------------
__global__ __launch_bounds__(256)
void gemm_bcdt(const float* __restrict__ x, const bf16_t* __restrict__ W,
               const float* __restrict__ b0, const float* __restrict__ b1,
               const float* __restrict__ b2,
               bf16_t* __restrict__ o0h, bf16_t* __restrict__ o1h,
               float* __restrict__ o2f)
{
    constexpr int K = kDModel;
    __shared__ __bf16 AstS[32 * 32];     // [row][k]
    __shared__ __bf16 WstS[160 * 32];    // [n][k]
    const int tid  = threadIdx.x;
    const int lane = tid & 63;
    const int wave = tid >> 6;
    const int wm = (wave >> 1) * 16;     // 0 or 16
    const int wn = (wave & 1) * 80;      // 0 or 80
    const int l15 = lane & 15, quad = lane >> 4;
    const int m0 = blockIdx.x * 32;
    const int ar = tid >> 3;             // A stage: row 0..31
    const int ac = (tid & 7) * 4;        // A stage: k-col 0,4,..,28

    f32x4 acc[5];
    #pragma unroll
    for (int j = 0; j < 5; ++j) acc[j] = (f32x4){0.f, 0.f, 0.f, 0.f};

    for (int k0 = 0; k0 < K; k0 += 32) {
        // A: fp32 load + cvt -> LDS (reg-staged)
        const float4 av = *reinterpret_cast<const float4*>(
            x + (size_t)(m0 + ar) * K + k0 + ac);
        bf16x4 a4;
        a4[0] = (__bf16)av.x; a4[1] = (__bf16)av.y;
        a4[2] = (__bf16)av.z; a4[3] = (__bf16)av.w;
        *reinterpret_cast<bf16x4*>(&AstS[ar * 32 + ac]) = a4;
        // W: 160x32 bf16 = 640 16B units (wave-uniform tail branch)
        #pragma unroll
        for (int e = 0; e < 3; ++e) {
            const int u = e * 256 + tid;
            if (u < 640)
                gload_lds16(W + (size_t)(u >> 2) * K + k0 + (u & 3) * 8, WstS + u * 8);
        }
        __syncthreads();
        bf16x8 af, bfr[5];
        af = *reinterpret_cast<const bf16x8*>(&AstS[(wm + l15) * 32 + quad * 8]);
        #pragma unroll
        for (int nf = 0; nf < 5; ++nf)
            bfr[nf] = *reinterpret_cast<const bf16x8*>(&WstS[(wn + nf * 16 + l15) * 32 + quad * 8]);
        #pragma unroll
        for (int nf = 0; nf < 5; ++nf)
            acc[nf] = __builtin_amdgcn_mfma_f32_16x16x32_bf16(af, bfr[nf], acc[nf], 0, 0, 0);
        __syncthreads();
    }

    // C/D layout: col = lane&15, row = quad*4 + reg  [m89-verified]
    #pragma unroll
    for (int reg = 0; reg < 4; ++reg) {
        const int r = m0 + wm + quad * 4 + reg;
        #pragma unroll
        for (int nf = 0; nf < 5; ++nf) {
            const float v = acc[nf][reg];
            const int n = wn + nf * 16 + l15;
            if (n < 64) {
                o0h[(size_t)r * 64 + n] = (bf16_t)(v + b0[n]);
            } else if (n < 128) {
                o1h[(size_t)r * 64 + (n - 64)] = (bf16_t)(v + b1[n - 64]);
            } else {
                float z = v + b2[n - 128];
                o2f[(size_t)r * 32 + (n - 128)] = (z > 20.f) ? z : log1pf(expf(z));
            }
        }
    }
}

// ---------------------------------------------------------------------------
// Out-projection GEMM — R2-measured config (69-75 us band, MfmaUtil ~40%,
// FETCH 49.2 MB, VGPR 92): 256x256 tile, BK=32, 8 waves, 16x16x32 MFMA,
// triple-buffered LDS (96KB), counted vmcnt(4), slot-major (conflict-free),
// m-panel-per-XCD swizzle. DO NOT PERTURB (R4: 32x32 shape switch = +14 us).
// ---------------------------------------------------------------------------
__global__ __launch_bounds__(512, 2)
void gemm256_out(const bf16_t* __restrict__ Ap, const bf16_t* __restrict__ Bp,
                 const float* __restrict__ bias, float* __restrict__ C)
{
    constexpr int M = 8192, N = 2048, NT = 2048 / 32;  // 64 K-tiles
    __shared__ __bf16 Ab[3][4 * 256 * 8];   // [buf][slot*256 + row][8]
    __shared__ __bf16 Bb[3][4 * 256 * 8];
    const int tid  = threadIdx.x;
    const int lane = tid & 63;
    const int wave = tid >> 6;
    const int l15 = lane & 15, quad = lane >> 4;
    const int bid = blockIdx.x;
    const int mt = (bid & 7) * 4 + ((bid >> 3) & 3);   // 0..31
    const int nt = bid >> 5;                           // 0..7
    const int m0 = mt * 256;
    const int n0 = nt * 256;
    const int wm = (wave >> 2) * 128;   // 0 or 128
    const int wn = (wave & 3) * 64;     // 0,64,128,192

    const int u0 = tid, u1 = tid + 512;   // staging 16B units
    auto stage = [&](int t2, int stb) {
        const int ks0 = t2 * 4;
        const bf16_t* As = Ap + ((size_t)ks0 * M + m0) * 8;
        const bf16_t* Bs = Bp + ((size_t)ks0 * N + n0) * 8;
        __bf16* Al = &Ab[stb][0];
        __bf16* Bl = &Bb[stb][0];
        gload_lds16(As + ((size_t)(u0 >> 8) * M + (u0 & 255)) * 8, Al + u0 * 8);
        gload_lds16(As + ((size_t)(u1 >> 8) * M + (u1 & 255)) * 8, Al + u1 * 8);
        gload_lds16(Bs + ((size_t)(u0 >> 8) * N + (u0 & 255)) * 8, Bl + u0 * 8);
        gload_lds16(Bs + ((size_t)(u1 >> 8) * N + (u1 & 255)) * 8, Bl + u1 * 8);
    };

    f32x4 acc[8][4];
    #pragma unroll
    for (int i = 0; i < 8; ++i)
        #pragma unroll
        for (int j = 0; j < 4; ++j)
            acc[i][j] = (f32x4){0.f, 0.f, 0.f, 0.f};

    stage(0, 0);
    stage(1, 1);
    asm volatile("s_waitcnt vmcnt(4)" ::: "memory");
    __builtin_amdgcn_s_barrier();

    int cur = 0;
    for (int t = 0; t < NT; ++t) {
        const __bf16* Ac = &Ab[cur][0];
        const __bf16* Bc = &Bb[cur][0];
        int stb = cur + 2; if (stb >= 3) stb -= 3;

        // ---- phase A: frags (rows wm..wm+63) + all B frags; prefetch t+2
        bf16x8 af[4], bfr[4];
        #pragma unroll
        for (int mi = 0; mi < 4; ++mi)
            af[mi] = *reinterpret_cast<const bf16x8*>(
                &Ac[(quad * 256 + wm + mi * 16 + l15) * 8]);
        #pragma unroll
        for (int nj = 0; nj < 4; ++nj)
            bfr[nj] = *reinterpret_cast<const bf16x8*>(
                &Bc[(quad * 256 + wn + nj * 16 + l15) * 8]);
        if (t < NT - 2) stage(t + 2, stb);
        __builtin_amdgcn_s_setprio(1);
        #pragma unroll
        for (int mi = 0; mi < 4; ++mi)
            #pragma unroll
            for (int nj = 0; nj < 4; ++nj)
                acc[mi][nj] = __builtin_amdgcn_mfma_f32_16x16x32_bf16(
                    af[mi], bfr[nj], acc[mi][nj], 0, 0, 0);
        __builtin_amdgcn_s_setprio(0);

        // ---- phase B: frags (rows wm+64..wm+127), reuse B frags
        #pragma unroll
        for (int mi = 0; mi < 4; ++mi)
            af[mi] = *reinterpret_cast<const bf16x8*>(
                &Ac[(quad * 256 + wm + 64 + mi * 16 + l15) * 8]);
        __builtin_amdgcn_s_setprio(1);
        #pragma unroll
        for (int mi = 0; mi < 4; ++mi)
            #pragma unroll
            for (int nj = 0; nj < 4; ++nj)
                acc[4 + mi][nj] = __builtin_amdgcn_mfma_f32_16x16x32_bf16(
                    af[mi], bfr[nj], acc[4 + mi][nj], 0, 0, 0);
        __builtin_amdgcn_s_setprio(0);

        // ---- tile boundary: tile t+1 landed; t+2's 4 loads may fly
        if (t < NT - 2) {
            asm volatile("s_waitcnt vmcnt(4)" ::: "memory");
        } else if (t < NT - 1) {
            asm volatile("s_waitcnt vmcnt(0)" ::: "memory");
        }
        if (t < NT - 1) __builtin_amdgcn_s_barrier();
        cur = cur + 1; if (cur == 3) cur = 0;
    }

    // epilogue: C = acc + bias
    float bia[4];
    #pragma unroll
    for (int nj = 0; nj < 4; ++nj) bia[nj] = bias[n0 + wn + nj * 16 + l15];
    #pragma unroll
    for (int mi = 0; mi < 8; ++mi) {
        #pragma unroll
        for (int reg = 0; reg < 4; ++reg) {
            const int r = m0 + wm + mi * 16 + quad * 4 + reg;
            #pragma unroll
            for (int nj = 0; nj < 4; ++nj) {
                const int c = n0 + wn + nj * 16 + l15;
                C[(size_t)r * N + c] = acc[mi][nj][reg] + bia[nj];
            }
        }
    }
}

// ---------------------------------------------------------------------------
// Prep (packs only — x cvt ELIMINATED): pack out_w slot-major (2048 blocks) |
// pack [B_w;C_w;dt_w] bf16 [160][2048] (1280 blocks).
// ---------------------------------------------------------------------------
__global__ __launch_bounds__(256)
void prep_fused(const float* __restrict__ W, bf16_t* __restrict__ Wp,
                const float* __restrict__ B_w, const float* __restrict__ C_w,
                const float* __restrict__ dt_w, bf16_t* __restrict__ wcat)
{
    const int bid = blockIdx.x;
    if (bid < 2048) {
        // pack_wob: fp32 [2048][2048] -> slot-major bf16 Wp[ks][n][8]
        const int idx = bid * 256 + threadIdx.x;
        const int n = idx >> 8, ks = idx & 255;
        const float4 v0 = *reinterpret_cast<const float4*>(W + (size_t)n * 2048 + ks * 8);
        const float4 v1 = *reinterpret_cast<const float4*>(W + (size_t)n * 2048 + ks * 8 + 4);
        bf16x8 o;
        o[0] = (__bf16)v0.x; o[1] = (__bf16)v0.y; o[2] = (__bf16)v0.z; o[3] = (__bf16)v0.w;
        o[4] = (__bf16)v1.x; o[5] = (__bf16)v1.y; o[6] = (__bf16)v1.z; o[7] = (__bf16)v1.w;
        *reinterpret_cast<bf16x8*>(Wp + ((size_t)ks * 2048 + n) * 8) = o;
    } else {
        // pack_w: concat [B_w;C_w;dt_w] bf16 [160][2048]
        const int idx = (bid - 2048) * 256 + threadIdx.x;
        const int r = idx >> 11, k = idx & 2047;
        float v;
        if (r < 64)       v = B_w[r * 2048 + k];
        else if (r < 128) v = C_w[(r - 64) * 2048 + k];
        else              v = dt_w[(r - 128) * 2048 + k];
        wcat[idx] = (bf16_t)v;
    }
}

// ---------------------------------------------------------------------------
// Mid fused (all 3 depend only on gemm_bcdt outputs; saves 2 launch gaps):
//  branch 0 (1024 blocks): dtcumsum — Acs[l] = cumsum(dt*A)
//  branch 1 (  32 blocks): bT — B chunk transpose
//  branch 2 (1024 blocks): xdtT — fp32 x * dt, transposed  [x read fp32 now]
// ---------------------------------------------------------------------------
__global__ __launch_bounds__(256)
void mid_fused(const float* __restrict__ dtm, const float* __restrict__ A_log,
               float* __restrict__ Acs, const bf16_t* __restrict__ Bb16,
               bf16_t* __restrict__ bTg, const float* __restrict__ x,
               bf16_t* __restrict__ xdtT)
{
    const int bid = blockIdx.x;
    const int tid = threadIdx.x;
    if (bid < 1024) {
        // dtcumsum: blk = (bi*kHeads+hi)*kNChunk + ci
        const int ci = bid & (kNChunk - 1);
        const int hi = (bid >> 4) & (kHeads - 1);
        const int bi = bid >> 9;
        const float Ah = -expf(A_log[hi]);
        __shared__ float s[kChunk];
        s[tid] = dtm[((size_t)bi * kSeq + ci * kChunk + tid) * kHeads + hi] * Ah;
        __syncthreads();
        for (int off = 1; off < kChunk; off <<= 1) {
            const float add = (tid >= off) ? s[tid - off] : 0.f;
            __syncthreads();
            s[tid] += add;
            __syncthreads();
        }
        Acs[((size_t)(bi * kHeads + hi) * kNChunk + ci) * kChunk + tid] = s[tid];
    } else if (bid < 1024 + 32) {
        // bT: bTg[b,c][n][l] = Bb16[(b,c,l)][n]
        const int blk = bid - 1024;
        const int ci = blk & (kNChunk - 1);
        const int bi = blk >> 4;
        const size_t rowbase = (size_t)bi * kSeq + ci * kChunk;
        __shared__ __bf16 T[64 * 264];
        bf16x8 v[8];
        #pragma unroll
        for (int e = 0; e < 8; ++e)
            v[e] = *reinterpret_cast<const bf16x8*>(Bb16 + (rowbase + tid) * 64 + e * 8);
        #pragma unroll
        for (int e = 0; e < 8; ++e)
            #pragma unroll
            for (int j = 0; j < 8; ++j)
                T[(e * 8 + j) * 264 + tid] = v[e][j];
        __syncthreads();
        const int n = tid >> 2, seg = (tid & 3) * 64;
        bf16_t* dst = bTg + ((size_t)(bi * kNChunk + ci)) * (64 * 256) + n * 256 + seg;
        #pragma unroll
        for (int j = 0; j < 8; ++j) {
            *reinterpret_cast<bf16x8*>(dst + j * 8) =
                *reinterpret_cast<const bf16x8*>(&T[n * 264 + seg + j * 8]);
        }
    } else {
        // xdtT: blk = (bi*16+ci)*32+hi ; x is fp32
        const int blk = bid - 1024 - 32;
        const int hi = blk & (kHeads - 1);
        const int ci = (blk >> 5) & (kNChunk - 1);
        const int bi = blk >> 9;
        const size_t rowbase = (size_t)bi * kSeq + ci * kChunk;
        __shared__ __bf16 T[64 * 264];
        const float d = dtm[(rowbase + tid) * kHeads + hi];
        const float* xs = x + (rowbase + tid) * kDModel + hi * kP;
        #pragma unroll
        for (int e = 0; e < 8; ++e) {
            const float4 a = *reinterpret_cast<const float4*>(xs + e * 8);
            const float4 b = *reinterpret_cast<const float4*>(xs + e * 8 + 4);
            T[(e * 8 + 0) * 264 + tid] = (__bf16)(a.x * d);
            T[(e * 8 + 1) * 264 + tid] = (__bf16)(a.y * d);
            T[(e * 8 + 2) * 264 + tid] = (__bf16)(a.z * d);
            T[(e * 8 + 3) * 264 + tid] = (__bf16)(a.w * d);
            T[(e * 8 + 4) * 264 + tid] = (__bf16)(b.x * d);
            T[(e * 8 + 5) * 264 + tid] = (__bf16)(b.y * d);
            T[(e * 8 + 6) * 264 + tid] = (__bf16)(b.z * d);
            T[(e * 8 + 7) * 264 + tid] = (__bf16)(b.w * d);
        }
        __syncthreads();
        const int p = tid >> 2, seg = (tid & 3) * 64;
        bf16_t* dst = xdtT + (size_t)blk * (64 * 256) + p * 256 + seg;
        #pragma unroll
        for (int j = 0; j < 8; ++j) {
            *reinterpret_cast<bf16x8*>(dst + j * 8) =
                *reinterpret_cast<const bf16x8*>(&T[p * 264 + seg + j * 8]);
        }
    }
}

// ---------------------------------------------------------------------------
// MFMA chunk states: states[(b,c,h)][p][n] = sum_l xdtT[p][l]*dec[l]*B[l][n]
// ---------------------------------------------------------------------------
__global__ __launch_bounds__(256)
void states_mfma(const bf16_t* __restrict__ xdtT, const bf16_t* __restrict__ bTg,
                 const float* __restrict__ Acs, float* __restrict__ states)
{
    const int blk = blockIdx.x;
    const int hi = blk & (kHeads - 1);
    const int ci = (blk >> 5) & (kNChunk - 1);
    const int bi = blk >> 9;
    __shared__ __bf16 Xa[64 * 264];
    __shared__ __bf16 Bt[64 * 264];
    __shared__ float dec[kChunk];
    const int tid = threadIdx.x;
    const int lane = tid & 63;
    const int wave = tid >> 6;
    const int l15 = lane & 15, quad = lane >> 4;

    const float* acs = Acs + ((size_t)(bi * kHeads + hi) * kNChunk + ci) * kChunk;
    dec[tid] = expf(acs[kChunk - 1] - acs[tid]);   // <= 1
    __syncthreads();

    const bf16_t* bsrc = bTg + ((size_t)(bi * kNChunk + ci)) * (64 * 256);
    const bf16_t* xsrc = xdtT + (size_t)blk * (64 * 256);
    #pragma unroll
    for (int e = 0; e < 8; ++e) {
        const int u = e * 256 + tid;
        const int r = u >> 5, seg = (u & 31) * 8;
        *reinterpret_cast<bf16x8*>(&Bt[r * 264 + seg]) =
            *reinterpret_cast<const bf16x8*>(bsrc + r * 256 + seg);
        bf16x8 xv = *reinterpret_cast<const bf16x8*>(xsrc + r * 256 + seg);
        bf16x8 xo;
        #pragma unroll
        for (int j = 0; j < 8; ++j)
            xo[j] = (__bf16)((float)xv[j] * dec[seg + j]);
        *reinterpret_cast<bf16x8*>(&Xa[r * 264 + seg]) = xo;
    }
    __syncthreads();

    f32x4 acc[4];
    #pragma unroll
    for (int ni = 0; ni < 4; ++ni) acc[ni] = (f32x4){0.f, 0.f, 0.f, 0.f};
    #pragma unroll
    for (int kk = 0; kk < 8; ++kk) {
        const bf16x8 af = *reinterpret_cast<const bf16x8*>(
            &Xa[(wave * 16 + l15) * 264 + kk * 32 + quad * 8]);
        #pragma unroll
        for (int ni = 0; ni < 4; ++ni) {
            const bf16x8 bf = *reinterpret_cast<const bf16x8*>(
                &Bt[(ni * 16 + l15) * 264 + kk * 32 + quad * 8]);
            acc[ni] = __builtin_amdgcn_mfma_f32_16x16x32_bf16(af, bf, acc[ni], 0, 0, 0);
        }
    }
    float* sp = states + (size_t)blk * (kP * kState);
    #pragma unroll
    for (int reg = 0; reg < 4; ++reg) {
        const int p = wave * 16 + quad * 4 + reg;
        #pragma unroll
        for (int ni = 0; ni < 4; ++ni)
            sp[(size_t)p * kState + ni * 16 + l15] = acc[ni][reg];
    }
}

// prevs[b,0,h]=0 ; prevs[b,c,h] = exp(a[c-1])*prevs[b,c-1,h] + states[b,c-1,h]
__global__ __launch_bounds__(256)
void chunkscan_kernel(const float* __restrict__ states, const float* __restrict__ Acs,
                      bf16_t* __restrict__ prevsb)
{
    const int q  = blockIdx.x & 15;
    const int hi = (blockIdx.x >> 4) & (kHeads - 1);
    const int bi = blockIdx.x >> 9;
    const int e  = q * 256 + threadIdx.x;          // element in [0, 4096)
    __shared__ float ea[kNChunk];
    if (threadIdx.x < kNChunk)
        ea[threadIdx.x] = expf(Acs[((size_t)(bi * kHeads + hi) * kNChunk + threadIdx.x)
                                   * kChunk + kChunk - 1]);
    __syncthreads();
    float P = 0.f;
    prevsb[((size_t)(bi * kNChunk + 0) * kHeads + hi) * (kP * kState) + e] = (bf16_t)0.f;
    for (int c = 1; c < kNChunk; ++c) {
        P = fmaf(ea[c - 1], P,
                 states[((size_t)(bi * kNChunk + (c - 1)) * kHeads + hi) * (kP * kState) + e]);
        prevsb[((size_t)(bi * kNChunk + c) * kHeads + hi) * (kP * kState) + e] = (bf16_t)P;
    }
}

// ---------------------------------------------------------------------------
// MFMA intra-chunk Y — split structure, wave-private Sp fence (R5-proven).
// Output SLOT-MAJOR: Yp[(hi*8+p/8)*kM + t][p%8].
// ---------------------------------------------------------------------------
__global__ __launch_bounds__(256)
void ychunk_mfma(const bf16_t* __restrict__ Bb16, const bf16_t* __restrict__ Cb16,
                 const bf16_t* __restrict__ xdtT, const float* __restrict__ Acs,
                 const bf16_t* __restrict__ prevsb, const float* __restrict__ dtm,
                 const float* __restrict__ Dvec, bf16_t* __restrict__ Yp)
{
    const int blk = blockIdx.x;                  // ((bi*16+ci)*32+hi)*4 + lt
    const int lt = blk & 3;
    const int hi = (blk >> 2) & (kHeads - 1);
    const int ci = (blk >> 7) & (kNChunk - 1);
    const int bi = blk >> 11;
    __shared__ float acs_s[kChunk];
    __shared__ float dts_s[64];
    __shared__ __bf16 Cs[64 * 72];
    __shared__ __bf16 Bs[64 * 72];   // P(bf16) first, then B s-tiles
    __shared__ __bf16 Xt[64 * 72];   // XdtT[p][s]
    __shared__ __bf16 Sp[64 * 72];   // S' [l][s] — wave-private rows
    const int tid = threadIdx.x;
    const int lane = tid & 63;
    const int wave = tid >> 6;
    const int l15 = lane & 15, quad = lane >> 4;
    const int mrow = wave * 16 + quad * 4;
    const size_t rowbase = (size_t)bi * kSeq + ci * kChunk;
    const bf16_t* xdsrc = xdtT + ((size_t)((bi * kNChunk + ci) * kHeads + hi)) * (64 * 256);

    acs_s[tid] = Acs[((size_t)(bi * kHeads + hi) * kNChunk + ci) * kChunk + tid];
    if (tid < 64) dts_s[tid] = dtm[(rowbase + lt * 64 + tid) * kHeads + hi];
    const bf16_t* pp = prevsb + ((size_t)(bi * kNChunk + ci) * kHeads + hi) * (kP * kState);
    #pragma unroll
    for (int e = 0; e < 2; ++e) {
        const int u = e * 256 + tid;
        const int r = u >> 3, seg = (u & 7) * 8;
        *reinterpret_cast<bf16x8*>(&Cs[r * 72 + seg]) =
            *reinterpret_cast<const bf16x8*>(Cb16 + (rowbase + lt * 64 + r) * 64 + seg);
        *reinterpret_cast<bf16x8*>(&Bs[r * 72 + seg]) =
            *reinterpret_cast<const bf16x8*>(pp + r * 64 + seg);
    }
    __syncthreads();

    bf16x8 af[2];
    af[0] = *reinterpret_cast<const bf16x8*>(&Cs[(wave * 16 + l15) * 72 + quad * 8]);
    af[1] = *reinterpret_cast<const bf16x8*>(&Cs[(wave * 16 + l15) * 72 + 32 + quad * 8]);

    // Y_off = (C @ P^T) * exp(acs[l])
    f32x4 yacc[4];
    #pragma unroll
    for (int ni = 0; ni < 4; ++ni) yacc[ni] = (f32x4){0.f, 0.f, 0.f, 0.f};
    #pragma unroll
    for (int ni = 0; ni < 4; ++ni) {
        const bf16x8 b0 = *reinterpret_cast<const bf16x8*>(&Bs[(ni * 16 + l15) * 72 + quad * 8]);
        const bf16x8 b1 = *reinterpret_cast<const bf16x8*>(&Bs[(ni * 16 + l15) * 72 + 32 + quad * 8]);
        yacc[ni] = __builtin_amdgcn_mfma_f32_16x16x32_bf16(af[0], b0, yacc[ni], 0, 0, 0);
        yacc[ni] = __builtin_amdgcn_mfma_f32_16x16x32_bf16(af[1], b1, yacc[ni], 0, 0, 0);
    }
    {
        float es[4];
        #pragma unroll
        for (int reg = 0; reg < 4; ++reg) es[reg] = expf(acs_s[lt * 64 + mrow + reg]);
        #pragma unroll
        for (int ni = 0; ni < 4; ++ni)
            #pragma unroll
            for (int reg = 0; reg < 4; ++reg) yacc[ni][reg] *= es[reg];
    }

    for (int st = 0; st <= lt; ++st) {
        __syncthreads();
        #pragma unroll
        for (int e = 0; e < 2; ++e) {
            const int u = e * 256 + tid;
            const int r = u >> 3, seg = (u & 7) * 8;
            *reinterpret_cast<bf16x8*>(&Bs[r * 72 + seg]) =
                *reinterpret_cast<const bf16x8*>(Bb16 + (rowbase + st * 64 + r) * 64 + seg);
            *reinterpret_cast<bf16x8*>(&Xt[r * 72 + seg]) =
                *reinterpret_cast<const bf16x8*>(xdsrc + r * 256 + st * 64 + seg);
        }
        __syncthreads();
        f32x4 sacc[4];
        #pragma unroll
        for (int ni = 0; ni < 4; ++ni) sacc[ni] = (f32x4){0.f, 0.f, 0.f, 0.f};
        #pragma unroll
        for (int ni = 0; ni < 4; ++ni) {
            const bf16x8 b0 = *reinterpret_cast<const bf16x8*>(&Bs[(ni * 16 + l15) * 72 + quad * 8]);
            const bf16x8 b1 = *reinterpret_cast<const bf16x8*>(&Bs[(ni * 16 + l15) * 72 + 32 + quad * 8]);
            sacc[ni] = __builtin_amdgcn_mfma_f32_16x16x32_bf16(af[0], b0, sacc[ni], 0, 0, 0);
            sacc[ni] = __builtin_amdgcn_mfma_f32_16x16x32_bf16(af[1], b1, sacc[ni], 0, 0, 0);
        }
        #pragma unroll
        for (int reg = 0; reg < 4; ++reg) {
            const int l = lt * 64 + mrow + reg;
            const float al = acs_s[l];
            #pragma unroll
            for (int ni = 0; ni < 4; ++ni) {
                const int scol = ni * 16 + l15;
                const int sg = st * 64 + scol;
                float v = sacc[ni][reg] * expf(al - acs_s[sg]);
                if (st == lt && sg > l) v = 0.f;
                Sp[(mrow + reg) * 72 + scol] = (__bf16)v;
            }
        }
        // same-wave fence (Sp rows are wave-private)
        asm volatile("s_waitcnt lgkmcnt(0)" ::: "memory");
        __builtin_amdgcn_sched_barrier(0);
        const bf16x8 as0 = *reinterpret_cast<const bf16x8*>(&Sp[(wave * 16 + l15) * 72 + quad * 8]);
        const bf16x8 as1 = *reinterpret_cast<const bf16x8*>(&Sp[(wave * 16 + l15) * 72 + 32 + quad * 8]);
        #pragma unroll
        for (int ni = 0; ni < 4; ++ni) {
            const bf16x8 x0 = *reinterpret_cast<const bf16x8*>(&Xt[(ni * 16 + l15) * 72 + quad * 8]);
            const bf16x8 x1 = *reinterpret_cast<const bf16x8*>(&Xt[(ni * 16 + l15) * 72 + 32 + quad * 8]);
            yacc[ni] = __builtin_amdgcn_mfma_f32_16x16x32_bf16(as0, x0, yacc[ni], 0, 0, 0);
            yacc[ni] = __builtin_amdgcn_mfma_f32_16x16x32_bf16(as1, x1, yacc[ni], 0, 0, 0);
        }
    }

    // epilogue: += D*x with x = xdt * (1/dt) from resident Xt (st==lt slice)
    const float Dh = Dvec[hi];
    #pragma unroll
    for (int reg = 0; reg < 4; ++reg) {
        const int lrow = mrow + reg;
        const size_t tg = rowbase + lt * 64 + lrow;
        const float dinv = 1.f / dts_s[lrow];
        #pragma unroll
        for (int ni = 0; ni < 4; ++ni) {
            const int p = ni * 16 + l15;
            const float xv = (float)Xt[p * 72 + lrow] * dinv;
            const float v = yacc[ni][reg] + Dh * xv;
            Yp[((size_t)(hi * 8 + (p >> 3)) * (size_t)kM + tg) * 8 + (p & 7)] = (bf16_t)v;
        }
    }
}

extern "C" void kernel_launch(void* const* d_in, const int* in_sizes, int n_in,
                              void* d_out, int out_size, void* d_ws, size_t ws_size,
                              hipStream_t stream)
{
    (void)in_sizes; (void)n_in; (void)out_size; (void)ws_size;
    const float* x     = (const float*)d_in[0];
    const float* A_log = (const float*)d_in[1];
    const float* Dvec  = (const float*)d_in[2];
    const float* B_w   = (const float*)d_in[3];
    const float* B_b   = (const float*)d_in[4];
    const float* C_w   = (const float*)d_in[5];
    const float* C_b   = (const float*)d_in[6];
    const float* dt_w  = (const float*)d_in[7];
    const float* dt_b  = (const float*)d_in[8];
    const float* out_w = (const float*)d_in[9];
    const float* out_b = (const float*)d_in[10];
    float* out = (float*)d_out;

    // workspace layout (xb region kept as Y; no pre-cvt of x anymore)
    float* ws = (float*)d_ws;
    float* dtm    = ws;                                                  // 2*4096*32
    float* Acs    = dtm + (size_t)kM * kHeads;                           // 2*32*16*256
    float* states = Acs + (size_t)kBatch * kHeads * kNChunk * kChunk;    // fp32 states
    bf16_t* prevsb = (bf16_t*)(states + (size_t)kBatch * kNChunk * kHeads * kP * kState);
    bf16_t* Y     = prevsb + (size_t)kBatch * kNChunk * kHeads * kP * kState;  // slot-major
    bf16_t* Bb16  = Y + (size_t)kM * kDModel;         // [t][64]
    bf16_t* Cb16  = Bb16 + (size_t)kM * kState;       // [t][64]
    bf16_t* xdtT  = Cb16 + (size_t)kM * kState;       // [(b,c,h)][64][256]
    bf16_t* bTg   = xdtT + (size_t)kM * kDModel;      // [(b,c)][64][256]
    bf16_t* wcat  = bTg + (size_t)kBatch * kNChunk * kState * kChunk;    // [160][2048]
    bf16_t* wob   = wcat + (size_t)160 * kDModel;     // bf16 out_w, slot-major

    const dim3 blk(256);
    // packs only (x cvt eliminated)
    prep_fused<<<dim3(2048 + 1280), blk, 0, stream>>>(out_w, wob, B_w, C_w, dt_w, wcat);
    // B/C/dt projection from fp32 x, BN=160 no-waste, 256 blocks
    gemm_bcdt<<<dim3(kM / 32), blk, 0, stream>>>(x, wcat, B_b, C_b, dt_b,
                                                 Bb16, Cb16, dtm);
    // fused: dtcumsum (1024) | bT (32) | xdtT from fp32 x (1024)
    mid_fused<<<dim3(1024 + 32 + 1024), blk, 0, stream>>>(
        dtm, A_log, Acs, Bb16, bTg, x, xdtT);
    states_mfma<<<dim3(kBatch * kNChunk * kHeads), blk, 0, stream>>>(xdtT, bTg, Acs, states);
    chunkscan_kernel<<<dim3(kBatch * kHeads * 16), blk, 0, stream>>>(states, Acs, prevsb);
    ychunk_mfma<<<dim3(kBatch * kNChunk * kHeads * 4), blk, 0, stream>>>(
        Bb16, Cb16, xdtT, Acs, prevsb, dtm, Dvec, Y);
    gemm256_out<<<dim3(256), dim3(512), 0, stream>>>(Y, wob, out_b, out);
}

// Round 7
// 350.593 us; speedup vs baseline: 1.0163x; 1.0163x over previous
//
#include <hip/hip_runtime.h>
#include <hip/hip_bf16.h>
#include <math.h>

namespace {
constexpr int kDModel = 2048;
constexpr int kHeads  = 32;
constexpr int kState  = 64;
constexpr int kP      = 64;    // head dim = D_MODEL / N_HEADS
constexpr int kChunk  = 256;
constexpr int kNChunk = 16;    // SEQLEN / CHUNK
constexpr int kBatch  = 2;
constexpr int kSeq    = 4096;
constexpr int kM      = kBatch * kSeq;  // 8192 rows
}

typedef __bf16 bf16_t;
typedef __attribute__((ext_vector_type(8))) __bf16 bf16x8;
typedef __attribute__((ext_vector_type(4))) __bf16 bf16x4;
typedef __attribute__((ext_vector_type(4))) float f32x4;

__device__ __forceinline__ void gload_lds16(const void* g, void* l) {
    __builtin_amdgcn_global_load_lds(
        (const __attribute__((address_space(1))) void*)g,
        (__attribute__((address_space(3))) void*)l,
        16, 0, 0);
}

// ---------------------------------------------------------------------------
// B/C/dt projection GEMM v3: gemm256-proven pipeline skeleton (triple-buffer,
// counted vmcnt(4), raw s_barrier, setprio) applied to the 32x160 tile.
// A staged as fp32 slot-major via gload_lds (cvt->bf16 at fragment time);
// W staged slot-major bf16, padded to 192 rows so staging is a uniform
// 3 units/thread (rows 160-191 staged but never read by MFMA).
// 4 gload_lds/thread/tile total -> vmcnt(4) == "previous tile landed".
// ---------------------------------------------------------------------------
__global__ __launch_bounds__(256)
void gemm_bcdt(const float* __restrict__ x, const bf16_t* __restrict__ W,
               const float* __restrict__ b0, const float* __restrict__ b1,
               const float* __restrict__ b2,
               bf16_t* __restrict__ o0h, bf16_t* __restrict__ o1h,
               float* __restrict__ o2f)
{
    constexpr int K = kDModel;
    constexpr int NT = K / 32;            // 64 K-tiles
    __shared__ float  Ast[3][256 * 4];    // [buf][unit][4 fp32]  : 4 KB/buf
    __shared__ __bf16 Wst[3][768 * 8];    // [buf][unit][8 bf16] : 12 KB/buf
    const int tid  = threadIdx.x;
    const int lane = tid & 63;
    const int wave = tid >> 6;
    const int wm = (wave >> 1) * 16;      // 0 or 16
    const int wn = (wave & 1) * 80;       // 0 or 80
    const int l15 = lane & 15, quad = lane >> 4;
    const int m0 = blockIdx.x * 32;
    const int aks = tid >> 5, arow = tid & 31;   // A slot-major: [ks8][row32]

    auto stage = [&](int t2, int sb) {
        const int k0 = t2 * 32;
        // A: 256 units, 1/thread. dest linear u*16B; src per-lane fp32.
        gload_lds16(x + (size_t)(m0 + arow) * K + k0 + aks * 4, &Ast[sb][tid * 4]);
        // W: 768 units (4 ks-slots x 192 rows), 3/thread.
        #pragma unroll
        for (int e = 0; e < 3; ++e) {
            const int u = e * 256 + tid;
            const int ks = u / 192;
            const int n  = u - ks * 192;
            gload_lds16(W + (size_t)n * K + k0 + ks * 8, &Wst[sb][u * 8]);
        }
    };

    f32x4 acc[5];
    #pragma unroll
    for (int j = 0; j < 5; ++j) acc[j] = (f32x4){0.f, 0.f, 0.f, 0.f};

    stage(0, 0);
    stage(1, 1);
    asm volatile("s_waitcnt vmcnt(4)" ::: "memory");
    __builtin_amdgcn_s_barrier();

    int cur = 0;
    for (int t = 0; t < NT; ++t) {
        const float*  Ac = &Ast[cur][0];
        const __bf16* Wc = &Wst[cur][0];
        int stb = cur + 2; if (stb >= 3) stb -= 3;

        // A-frag: 8 fp32 (slots quad*2, quad*2+1) -> cvt bf16x8
        const float4 a0 = *reinterpret_cast<const float4*>(
            &Ac[((quad * 2 + 0) * 32 + wm + l15) * 4]);
        const float4 a1 = *reinterpret_cast<const float4*>(
            &Ac[((quad * 2 + 1) * 32 + wm + l15) * 4]);
        bf16x8 af;
        af[0] = (__bf16)a0.x; af[1] = (__bf16)a0.y;
        af[2] = (__bf16)a0.z; af[3] = (__bf16)a0.w;
        af[4] = (__bf16)a1.x; af[5] = (__bf16)a1.y;
        af[6] = (__bf16)a1.z; af[7] = (__bf16)a1.w;
        bf16x8 bfr[5];
        #pragma unroll
        for (int nf = 0; nf < 5; ++nf)
            bfr[nf] = *reinterpret_cast<const bf16x8*>(
                &Wc[(quad * 192 + wn + nf * 16 + l15) * 8]);
        if (t < NT - 2) stage(t + 2, stb);
        __builtin_amdgcn_s_setprio(1);
        #pragma unroll
        for (int nf = 0; nf < 5; ++nf)
            acc[nf] = __builtin_amdgcn_mfma_f32_16x16x32_bf16(af, bfr[nf], acc[nf], 0, 0, 0);
        __builtin_amdgcn_s_setprio(0);

        if (t < NT - 2) {
            asm volatile("s_waitcnt vmcnt(4)" ::: "memory");
        } else if (t < NT - 1) {
            asm volatile("s_waitcnt vmcnt(0)" ::: "memory");
        }
        if (t < NT - 1) __builtin_amdgcn_s_barrier();
        cur = cur + 1; if (cur == 3) cur = 0;
    }

    // C/D layout: col = lane&15, row = quad*4 + reg  [m89-verified]
    #pragma unroll
    for (int reg = 0; reg < 4; ++reg) {
        const int r = m0 + wm + quad * 4 + reg;
        #pragma unroll
        for (int nf = 0; nf < 5; ++nf) {
            const float v = acc[nf][reg];
            const int n = wn + nf * 16 + l15;
            if (n < 64) {
                o0h[(size_t)r * 64 + n] = (bf16_t)(v + b0[n]);
            } else if (n < 128) {
                o1h[(size_t)r * 64 + (n - 64)] = (bf16_t)(v + b1[n - 64]);
            } else {
                float z = v + b2[n - 128];
                o2f[(size_t)r * 32 + (n - 128)] = (z > 20.f) ? z : log1pf(expf(z));
            }
        }
    }
}

// ---------------------------------------------------------------------------
// Out-projection GEMM — R2-measured config (69-76 us band, MfmaUtil ~40%,
// FETCH 49.2 MB, VGPR 92). FROZEN (R4: shape switch = +14 us).
// ---------------------------------------------------------------------------
__global__ __launch_bounds__(512, 2)
void gemm256_out(const bf16_t* __restrict__ Ap, const bf16_t* __restrict__ Bp,
                 const float* __restrict__ bias, float* __restrict__ C)
{
    constexpr int M = 8192, N = 2048, NT = 2048 / 32;  // 64 K-tiles
    __shared__ __bf16 Ab[3][4 * 256 * 8];   // [buf][slot*256 + row][8]
    __shared__ __bf16 Bb[3][4 * 256 * 8];
    const int tid  = threadIdx.x;
    const int lane = tid & 63;
    const int wave = tid >> 6;
    const int l15 = lane & 15, quad = lane >> 4;
    const int bid = blockIdx.x;
    const int mt = (bid & 7) * 4 + ((bid >> 3) & 3);   // 0..31
    const int nt = bid >> 5;                           // 0..7
    const int m0 = mt * 256;
    const int n0 = nt * 256;
    const int wm = (wave >> 2) * 128;   // 0 or 128
    const int wn = (wave & 3) * 64;     // 0,64,128,192

    const int u0 = tid, u1 = tid + 512;   // staging 16B units
    auto stage = [&](int t2, int stb) {
        const int ks0 = t2 * 4;
        const bf16_t* As = Ap + ((size_t)ks0 * M + m0) * 8;
        const bf16_t* Bs = Bp + ((size_t)ks0 * N + n0) * 8;
        __bf16* Al = &Ab[stb][0];
        __bf16* Bl = &Bb[stb][0];
        gload_lds16(As + ((size_t)(u0 >> 8) * M + (u0 & 255)) * 8, Al + u0 * 8);
        gload_lds16(As + ((size_t)(u1 >> 8) * M + (u1 & 255)) * 8, Al + u1 * 8);
        gload_lds16(Bs + ((size_t)(u0 >> 8) * N + (u0 & 255)) * 8, Bl + u0 * 8);
        gload_lds16(Bs + ((size_t)(u1 >> 8) * N + (u1 & 255)) * 8, Bl + u1 * 8);
    };

    f32x4 acc[8][4];
    #pragma unroll
    for (int i = 0; i < 8; ++i)
        #pragma unroll
        for (int j = 0; j < 4; ++j)
            acc[i][j] = (f32x4){0.f, 0.f, 0.f, 0.f};

    stage(0, 0);
    stage(1, 1);
    asm volatile("s_waitcnt vmcnt(4)" ::: "memory");
    __builtin_amdgcn_s_barrier();

    int cur = 0;
    for (int t = 0; t < NT; ++t) {
        const __bf16* Ac = &Ab[cur][0];
        const __bf16* Bc = &Bb[cur][0];
        int stb = cur + 2; if (stb >= 3) stb -= 3;

        // ---- phase A: frags (rows wm..wm+63) + all B frags; prefetch t+2
        bf16x8 af[4], bfr[4];
        #pragma unroll
        for (int mi = 0; mi < 4; ++mi)
            af[mi] = *reinterpret_cast<const bf16x8*>(
                &Ac[(quad * 256 + wm + mi * 16 + l15) * 8]);
        #pragma unroll
        for (int nj = 0; nj < 4; ++nj)
            bfr[nj] = *reinterpret_cast<const bf16x8*>(
                &Bc[(quad * 256 + wn + nj * 16 + l15) * 8]);
        if (t < NT - 2) stage(t + 2, stb);
        __builtin_amdgcn_s_setprio(1);
        #pragma unroll
        for (int mi = 0; mi < 4; ++mi)
            #pragma unroll
            for (int nj = 0; nj < 4; ++nj)
                acc[mi][nj] = __builtin_amdgcn_mfma_f32_16x16x32_bf16(
                    af[mi], bfr[nj], acc[mi][nj], 0, 0, 0);
        __builtin_amdgcn_s_setprio(0);

        // ---- phase B: frags (rows wm+64..wm+127), reuse B frags
        #pragma unroll
        for (int mi = 0; mi < 4; ++mi)
            af[mi] = *reinterpret_cast<const bf16x8*>(
                &Ac[(quad * 256 + wm + 64 + mi * 16 + l15) * 8]);
        __builtin_amdgcn_s_setprio(1);
        #pragma unroll
        for (int mi = 0; mi < 4; ++mi)
            #pragma unroll
            for (int nj = 0; nj < 4; ++nj)
                acc[4 + mi][nj] = __builtin_amdgcn_mfma_f32_16x16x32_bf16(
                    af[mi], bfr[nj], acc[4 + mi][nj], 0, 0, 0);
        __builtin_amdgcn_s_setprio(0);

        // ---- tile boundary: tile t+1 landed; t+2's 4 loads may fly
        if (t < NT - 2) {
            asm volatile("s_waitcnt vmcnt(4)" ::: "memory");
        } else if (t < NT - 1) {
            asm volatile("s_waitcnt vmcnt(0)" ::: "memory");
        }
        if (t < NT - 1) __builtin_amdgcn_s_barrier();
        cur = cur + 1; if (cur == 3) cur = 0;
    }

    // epilogue: C = acc + bias
    float bia[4];
    #pragma unroll
    for (int nj = 0; nj < 4; ++nj) bia[nj] = bias[n0 + wn + nj * 16 + l15];
    #pragma unroll
    for (int mi = 0; mi < 8; ++mi) {
        #pragma unroll
        for (int reg = 0; reg < 4; ++reg) {
            const int r = m0 + wm + mi * 16 + quad * 4 + reg;
            #pragma unroll
            for (int nj = 0; nj < 4; ++nj) {
                const int c = n0 + wn + nj * 16 + l15;
                C[(size_t)r * N + c] = acc[mi][nj][reg] + bia[nj];
            }
        }
    }
}

// ---------------------------------------------------------------------------
// Prep: pack out_w slot-major (2048 blocks) | pack [B_w;C_w;dt_w] bf16
// [192][2048] (1536 blocks; rows 160-191 zero — staging pad for bcdt v3).
// ---------------------------------------------------------------------------
__global__ __launch_bounds__(256)
void prep_fused(const float* __restrict__ W, bf16_t* __restrict__ Wp,
                const float* __restrict__ B_w, const float* __restrict__ C_w,
                const float* __restrict__ dt_w, bf16_t* __restrict__ wcat)
{
    const int bid = blockIdx.x;
    if (bid < 2048) {
        const int idx = bid * 256 + threadIdx.x;
        const int n = idx >> 8, ks = idx & 255;
        const float4 v0 = *reinterpret_cast<const float4*>(W + (size_t)n * 2048 + ks * 8);
        const float4 v1 = *reinterpret_cast<const float4*>(W + (size_t)n * 2048 + ks * 8 + 4);
        bf16x8 o;
        o[0] = (__bf16)v0.x; o[1] = (__bf16)v0.y; o[2] = (__bf16)v0.z; o[3] = (__bf16)v0.w;
        o[4] = (__bf16)v1.x; o[5] = (__bf16)v1.y; o[6] = (__bf16)v1.z; o[7] = (__bf16)v1.w;
        *reinterpret_cast<bf16x8*>(Wp + ((size_t)ks * 2048 + n) * 8) = o;
    } else {
        const int idx = (bid - 2048) * 256 + threadIdx.x;   // 192*2048
        const int r = idx >> 11, k = idx & 2047;
        float v = 0.f;
        if (r < 64)       v = B_w[r * 2048 + k];
        else if (r < 128) v = C_w[(r - 64) * 2048 + k];
        else if (r < 160) v = dt_w[(r - 128) * 2048 + k];
        wcat[idx] = (bf16_t)v;
    }
}

// ---------------------------------------------------------------------------
// Mid fused: dtcumsum (1024) | bT (32) | xdtT from fp32 x (1024).
// ---------------------------------------------------------------------------
__global__ __launch_bounds__(256)
void mid_fused(const float* __restrict__ dtm, const float* __restrict__ A_log,
               float* __restrict__ Acs, const bf16_t* __restrict__ Bb16,
               bf16_t* __restrict__ bTg, const float* __restrict__ x,
               bf16_t* __restrict__ xdtT)
{
    const int bid = blockIdx.x;
    const int tid = threadIdx.x;
    if (bid < 1024) {
        const int ci = bid & (kNChunk - 1);
        const int hi = (bid >> 4) & (kHeads - 1);
        const int bi = bid >> 9;
        const float Ah = -expf(A_log[hi]);
        __shared__ float s[kChunk];
        s[tid] = dtm[((size_t)bi * kSeq + ci * kChunk + tid) * kHeads + hi] * Ah;
        __syncthreads();
        for (int off = 1; off < kChunk; off <<= 1) {
            const float add = (tid >= off) ? s[tid - off] : 0.f;
            __syncthreads();
            s[tid] += add;
            __syncthreads();
        }
        Acs[((size_t)(bi * kHeads + hi) * kNChunk + ci) * kChunk + tid] = s[tid];
    } else if (bid < 1024 + 32) {
        const int blk = bid - 1024;
        const int ci = blk & (kNChunk - 1);
        const int bi = blk >> 4;
        const size_t rowbase = (size_t)bi * kSeq + ci * kChunk;
        __shared__ __bf16 T[64 * 264];
        bf16x8 v[8];
        #pragma unroll
        for (int e = 0; e < 8; ++e)
            v[e] = *reinterpret_cast<const bf16x8*>(Bb16 + (rowbase + tid) * 64 + e * 8);
        #pragma unroll
        for (int e = 0; e < 8; ++e)
            #pragma unroll
            for (int j = 0; j < 8; ++j)
                T[(e * 8 + j) * 264 + tid] = v[e][j];
        __syncthreads();
        const int n = tid >> 2, seg = (tid & 3) * 64;
        bf16_t* dst = bTg + ((size_t)(bi * kNChunk + ci)) * (64 * 256) + n * 256 + seg;
        #pragma unroll
        for (int j = 0; j < 8; ++j) {
            *reinterpret_cast<bf16x8*>(dst + j * 8) =
                *reinterpret_cast<const bf16x8*>(&T[n * 264 + seg + j * 8]);
        }
    } else {
        const int blk = bid - 1024 - 32;
        const int hi = blk & (kHeads - 1);
        const int ci = (blk >> 5) & (kNChunk - 1);
        const int bi = blk >> 9;
        const size_t rowbase = (size_t)bi * kSeq + ci * kChunk;
        __shared__ __bf16 T[64 * 264];
        const float d = dtm[(rowbase + tid) * kHeads + hi];
        const float* xs = x + (rowbase + tid) * kDModel + hi * kP;
        #pragma unroll
        for (int e = 0; e < 8; ++e) {
            const float4 a = *reinterpret_cast<const float4*>(xs + e * 8);
            const float4 b = *reinterpret_cast<const float4*>(xs + e * 8 + 4);
            T[(e * 8 + 0) * 264 + tid] = (__bf16)(a.x * d);
            T[(e * 8 + 1) * 264 + tid] = (__bf16)(a.y * d);
            T[(e * 8 + 2) * 264 + tid] = (__bf16)(a.z * d);
            T[(e * 8 + 3) * 264 + tid] = (__bf16)(a.w * d);
            T[(e * 8 + 4) * 264 + tid] = (__bf16)(b.x * d);
            T[(e * 8 + 5) * 264 + tid] = (__bf16)(b.y * d);
            T[(e * 8 + 6) * 264 + tid] = (__bf16)(b.z * d);
            T[(e * 8 + 7) * 264 + tid] = (__bf16)(b.w * d);
        }
        __syncthreads();
        const int p = tid >> 2, seg = (tid & 3) * 64;
        bf16_t* dst = xdtT + (size_t)blk * (64 * 256) + p * 256 + seg;
        #pragma unroll
        for (int j = 0; j < 8; ++j) {
            *reinterpret_cast<bf16x8*>(dst + j * 8) =
                *reinterpret_cast<const bf16x8*>(&T[p * 264 + seg + j * 8]);
        }
    }
}

// ---------------------------------------------------------------------------
// MFMA chunk states: states[(b,c,h)][p][n] = sum_l xdtT[p][l]*dec[l]*B[l][n]
// ---------------------------------------------------------------------------
__global__ __launch_bounds__(256)
void states_mfma(const bf16_t* __restrict__ xdtT, const bf16_t* __restrict__ bTg,
                 const float* __restrict__ Acs, float* __restrict__ states)
{
    const int blk = blockIdx.x;
    const int hi = blk & (kHeads - 1);
    const int ci = (blk >> 5) & (kNChunk - 1);
    const int bi = blk >> 9;
    __shared__ __bf16 Xa[64 * 264];
    __shared__ __bf16 Bt[64 * 264];
    __shared__ float dec[kChunk];
    const int tid = threadIdx.x;
    const int lane = tid & 63;
    const int wave = tid >> 6;
    const int l15 = lane & 15, quad = lane >> 4;

    const float* acs = Acs + ((size_t)(bi * kHeads + hi) * kNChunk + ci) * kChunk;
    dec[tid] = expf(acs[kChunk - 1] - acs[tid]);   // <= 1
    __syncthreads();

    const bf16_t* bsrc = bTg + ((size_t)(bi * kNChunk + ci)) * (64 * 256);
    const bf16_t* xsrc = xdtT + (size_t)blk * (64 * 256);
    #pragma unroll
    for (int e = 0; e < 8; ++e) {
        const int u = e * 256 + tid;
        const int r = u >> 5, seg = (u & 31) * 8;
        *reinterpret_cast<bf16x8*>(&Bt[r * 264 + seg]) =
            *reinterpret_cast<const bf16x8*>(bsrc + r * 256 + seg);
        bf16x8 xv = *reinterpret_cast<const bf16x8*>(xsrc + r * 256 + seg);
        bf16x8 xo;
        #pragma unroll
        for (int j = 0; j < 8; ++j)
            xo[j] = (__bf16)((float)xv[j] * dec[seg + j]);
        *reinterpret_cast<bf16x8*>(&Xa[r * 264 + seg]) = xo;
    }
    __syncthreads();

    f32x4 acc[4];
    #pragma unroll
    for (int ni = 0; ni < 4; ++ni) acc[ni] = (f32x4){0.f, 0.f, 0.f, 0.f};
    #pragma unroll
    for (int kk = 0; kk < 8; ++kk) {
        const bf16x8 af = *reinterpret_cast<const bf16x8*>(
            &Xa[(wave * 16 + l15) * 264 + kk * 32 + quad * 8]);
        #pragma unroll
        for (int ni = 0; ni < 4; ++ni) {
            const bf16x8 bf = *reinterpret_cast<const bf16x8*>(
                &Bt[(ni * 16 + l15) * 264 + kk * 32 + quad * 8]);
            acc[ni] = __builtin_amdgcn_mfma_f32_16x16x32_bf16(af, bf, acc[ni], 0, 0, 0);
        }
    }
    float* sp = states + (size_t)blk * (kP * kState);
    #pragma unroll
    for (int reg = 0; reg < 4; ++reg) {
        const int p = wave * 16 + quad * 4 + reg;
        #pragma unroll
        for (int ni = 0; ni < 4; ++ni)
            sp[(size_t)p * kState + ni * 16 + l15] = acc[ni][reg];
    }
}

// prevs[b,0,h]=0 ; prevs[b,c,h] = exp(a[c-1])*prevs[b,c-1,h] + states[b,c-1,h]
__global__ __launch_bounds__(256)
void chunkscan_kernel(const float* __restrict__ states, const float* __restrict__ Acs,
                      bf16_t* __restrict__ prevsb)
{
    const int q  = blockIdx.x & 15;
    const int hi = (blockIdx.x >> 4) & (kHeads - 1);
    const int bi = blockIdx.x >> 9;
    const int e  = q * 256 + threadIdx.x;          // element in [0, 4096)
    __shared__ float ea[kNChunk];
    if (threadIdx.x < kNChunk)
        ea[threadIdx.x] = expf(Acs[((size_t)(bi * kHeads + hi) * kNChunk + threadIdx.x)
                                   * kChunk + kChunk - 1]);
    __syncthreads();
    float P = 0.f;
    prevsb[((size_t)(bi * kNChunk + 0) * kHeads + hi) * (kP * kState) + e] = (bf16_t)0.f;
    for (int c = 1; c < kNChunk; ++c) {
        P = fmaf(ea[c - 1], P,
                 states[((size_t)(bi * kNChunk + (c - 1)) * kHeads + hi) * (kP * kState) + e]);
        prevsb[((size_t)(bi * kNChunk + c) * kHeads + hi) * (kP * kState) + e] = (bf16_t)P;
    }
}

// ---------------------------------------------------------------------------
// MFMA intra-chunk Y — split structure, wave-private Sp fence (R5-proven).
// NEW (T14 async-stage): B/Xt tiles for st+1 are loaded into REGISTERS during
// st's compute; ds_write at loop top. st=0 loads issued before the first
// barrier so they hide under Y_off. LDS unchanged (4 blocks/CU).
// ---------------------------------------------------------------------------
__global__ __launch_bounds__(256)
void ychunk_mfma(const bf16_t* __restrict__ Bb16, const bf16_t* __restrict__ Cb16,
                 const bf16_t* __restrict__ xdtT, const float* __restrict__ Acs,
                 const bf16_t* __restrict__ prevsb, const float* __restrict__ dtm,
                 const float* __restrict__ Dvec, bf16_t* __restrict__ Yp)
{
    const int blk = blockIdx.x;                  // ((bi*16+ci)*32+hi)*4 + lt
    const int lt = blk & 3;
    const int hi = (blk >> 2) & (kHeads - 1);
    const int ci = (blk >> 7) & (kNChunk - 1);
    const int bi = blk >> 11;
    __shared__ float acs_s[kChunk];
    __shared__ float dts_s[64];
    __shared__ __bf16 Cs[64 * 72];
    __shared__ __bf16 Bs[64 * 72];   // P(bf16) first, then B s-tiles
    __shared__ __bf16 Xt[64 * 72];   // XdtT[p][s]
    __shared__ __bf16 Sp[64 * 72];   // S' [l][s] — wave-private rows
    const int tid = threadIdx.x;
    const int lane = tid & 63;
    const int wave = tid >> 6;
    const int l15 = lane & 15, quad = lane >> 4;
    const int mrow = wave * 16 + quad * 4;
    const size_t rowbase = (size_t)bi * kSeq + ci * kChunk;
    const bf16_t* xdsrc = xdtT + ((size_t)((bi * kNChunk + ci) * kHeads + hi)) * (64 * 256);
    const int ur0 = tid >> 3,          useg0 = (tid & 7) * 8;
    const int ur1 = (256 + tid) >> 3,  useg1 = (tid & 7) * 8;   // u=256+tid: (u&7)==(tid&7)

    acs_s[tid] = Acs[((size_t)(bi * kHeads + hi) * kNChunk + ci) * kChunk + tid];
    if (tid < 64) dts_s[tid] = dtm[(rowbase + lt * 64 + tid) * kHeads + hi];
    const bf16_t* pp = prevsb + ((size_t)(bi * kNChunk + ci) * kHeads + hi) * (kP * kState);
    #pragma unroll
    for (int e = 0; e < 2; ++e) {
        const int r = e ? ur1 : ur0, seg = e ? useg1 : useg0;
        *reinterpret_cast<bf16x8*>(&Cs[r * 72 + seg]) =
            *reinterpret_cast<const bf16x8*>(Cb16 + (rowbase + lt * 64 + r) * 64 + seg);
        *reinterpret_cast<bf16x8*>(&Bs[r * 72 + seg]) =
            *reinterpret_cast<const bf16x8*>(pp + r * 64 + seg);
    }
    // T14: issue st=0 B/Xt loads now — they land during Y_off compute.
    bf16x8 rB0, rB1, rX0, rX1;
    rB0 = *reinterpret_cast<const bf16x8*>(Bb16 + (rowbase + ur0) * 64 + useg0);
    rB1 = *reinterpret_cast<const bf16x8*>(Bb16 + (rowbase + ur1) * 64 + useg1);
    rX0 = *reinterpret_cast<const bf16x8*>(xdsrc + ur0 * 256 + useg0);
    rX1 = *reinterpret_cast<const bf16x8*>(xdsrc + ur1 * 256 + useg1);
    __syncthreads();

    bf16x8 af[2];
    af[0] = *reinterpret_cast<const bf16x8*>(&Cs[(wave * 16 + l15) * 72 + quad * 8]);
    af[1] = *reinterpret_cast<const bf16x8*>(&Cs[(wave * 16 + l15) * 72 + 32 + quad * 8]);

    // Y_off = (C @ P^T) * exp(acs[l])
    f32x4 yacc[4];
    #pragma unroll
    for (int ni = 0; ni < 4; ++ni) yacc[ni] = (f32x4){0.f, 0.f, 0.f, 0.f};
    #pragma unroll
    for (int ni = 0; ni < 4; ++ni) {
        const bf16x8 b0 = *reinterpret_cast<const bf16x8*>(&Bs[(ni * 16 + l15) * 72 + quad * 8]);
        const bf16x8 b1 = *reinterpret_cast<const bf16x8*>(&Bs[(ni * 16 + l15) * 72 + 32 + quad * 8]);
        yacc[ni] = __builtin_amdgcn_mfma_f32_16x16x32_bf16(af[0], b0, yacc[ni], 0, 0, 0);
        yacc[ni] = __builtin_amdgcn_mfma_f32_16x16x32_bf16(af[1], b1, yacc[ni], 0, 0, 0);
    }
    {
        float es[4];
        #pragma unroll
        for (int reg = 0; reg < 4; ++reg) es[reg] = expf(acs_s[lt * 64 + mrow + reg]);
        #pragma unroll
        for (int ni = 0; ni < 4; ++ni)
            #pragma unroll
            for (int reg = 0; reg < 4; ++reg) yacc[ni][reg] *= es[reg];
    }

    for (int st = 0; st <= lt; ++st) {
        __syncthreads();   // prior readers of Bs/Xt done
        // write prefetched regs -> LDS (compiler inserts vmcnt for the loads)
        *reinterpret_cast<bf16x8*>(&Bs[ur0 * 72 + useg0]) = rB0;
        *reinterpret_cast<bf16x8*>(&Bs[ur1 * 72 + useg1]) = rB1;
        *reinterpret_cast<bf16x8*>(&Xt[ur0 * 72 + useg0]) = rX0;
        *reinterpret_cast<bf16x8*>(&Xt[ur1 * 72 + useg1]) = rX1;
        // issue next tile's loads — they land during this tile's compute
        if (st < lt) {
            rB0 = *reinterpret_cast<const bf16x8*>(Bb16 + (rowbase + (st + 1) * 64 + ur0) * 64 + useg0);
            rB1 = *reinterpret_cast<const bf16x8*>(Bb16 + (rowbase + (st + 1) * 64 + ur1) * 64 + useg1);
            rX0 = *reinterpret_cast<const bf16x8*>(xdsrc + ur0 * 256 + (st + 1) * 64 + useg0);
            rX1 = *reinterpret_cast<const bf16x8*>(xdsrc + ur1 * 256 + (st + 1) * 64 + useg1);
        }
        __syncthreads();
        f32x4 sacc[4];
        #pragma unroll
        for (int ni = 0; ni < 4; ++ni) sacc[ni] = (f32x4){0.f, 0.f, 0.f, 0.f};
        #pragma unroll
        for (int ni = 0; ni < 4; ++ni) {
            const bf16x8 b0 = *reinterpret_cast<const bf16x8*>(&Bs[(ni * 16 + l15) * 72 + quad * 8]);
            const bf16x8 b1 = *reinterpret_cast<const bf16x8*>(&Bs[(ni * 16 + l15) * 72 + 32 + quad * 8]);
            sacc[ni] = __builtin_amdgcn_mfma_f32_16x16x32_bf16(af[0], b0, sacc[ni], 0, 0, 0);
            sacc[ni] = __builtin_amdgcn_mfma_f32_16x16x32_bf16(af[1], b1, sacc[ni], 0, 0, 0);
        }
        #pragma unroll
        for (int reg = 0; reg < 4; ++reg) {
            const int l = lt * 64 + mrow + reg;
            const float al = acs_s[l];
            #pragma unroll
            for (int ni = 0; ni < 4; ++ni) {
                const int scol = ni * 16 + l15;
                const int sg = st * 64 + scol;
                float v = sacc[ni][reg] * expf(al - acs_s[sg]);
                if (st == lt && sg > l) v = 0.f;
                Sp[(mrow + reg) * 72 + scol] = (__bf16)v;
            }
        }
        // same-wave fence (Sp rows are wave-private)
        asm volatile("s_waitcnt lgkmcnt(0)" ::: "memory");
        __builtin_amdgcn_sched_barrier(0);
        const bf16x8 as0 = *reinterpret_cast<const bf16x8*>(&Sp[(wave * 16 + l15) * 72 + quad * 8]);
        const bf16x8 as1 = *reinterpret_cast<const bf16x8*>(&Sp[(wave * 16 + l15) * 72 + 32 + quad * 8]);
        #pragma unroll
        for (int ni = 0; ni < 4; ++ni) {
            const bf16x8 x0 = *reinterpret_cast<const bf16x8*>(&Xt[(ni * 16 + l15) * 72 + quad * 8]);
            const bf16x8 x1 = *reinterpret_cast<const bf16x8*>(&Xt[(ni * 16 + l15) * 72 + 32 + quad * 8]);
            yacc[ni] = __builtin_amdgcn_mfma_f32_16x16x32_bf16(as0, x0, yacc[ni], 0, 0, 0);
            yacc[ni] = __builtin_amdgcn_mfma_f32_16x16x32_bf16(as1, x1, yacc[ni], 0, 0, 0);
        }
    }

    // epilogue: += D*x with x = xdt * (1/dt) from resident Xt (st==lt slice)
    const float Dh = Dvec[hi];
    #pragma unroll
    for (int reg = 0; reg < 4; ++reg) {
        const int lrow = mrow + reg;
        const size_t tg = rowbase + lt * 64 + lrow;
        const float dinv = 1.f / dts_s[lrow];
        #pragma unroll
        for (int ni = 0; ni < 4; ++ni) {
            const int p = ni * 16 + l15;
            const float xv = (float)Xt[p * 72 + lrow] * dinv;
            const float v = yacc[ni][reg] + Dh * xv;
            Yp[((size_t)(hi * 8 + (p >> 3)) * (size_t)kM + tg) * 8 + (p & 7)] = (bf16_t)v;
        }
    }
}

extern "C" void kernel_launch(void* const* d_in, const int* in_sizes, int n_in,
                              void* d_out, int out_size, void* d_ws, size_t ws_size,
                              hipStream_t stream)
{
    (void)in_sizes; (void)n_in; (void)out_size; (void)ws_size;
    const float* x     = (const float*)d_in[0];
    const float* A_log = (const float*)d_in[1];
    const float* Dvec  = (const float*)d_in[2];
    const float* B_w   = (const float*)d_in[3];
    const float* B_b   = (const float*)d_in[4];
    const float* C_w   = (const float*)d_in[5];
    const float* C_b   = (const float*)d_in[6];
    const float* dt_w  = (const float*)d_in[7];
    const float* dt_b  = (const float*)d_in[8];
    const float* out_w = (const float*)d_in[9];
    const float* out_b = (const float*)d_in[10];
    float* out = (float*)d_out;

    // workspace layout
    float* ws = (float*)d_ws;
    float* dtm    = ws;                                                  // 2*4096*32
    float* Acs    = dtm + (size_t)kM * kHeads;                           // 2*32*16*256
    float* states = Acs + (size_t)kBatch * kHeads * kNChunk * kChunk;    // fp32 states
    bf16_t* prevsb = (bf16_t*)(states + (size_t)kBatch * kNChunk * kHeads * kP * kState);
    bf16_t* Y     = prevsb + (size_t)kBatch * kNChunk * kHeads * kP * kState;  // slot-major
    bf16_t* Bb16  = Y + (size_t)kM * kDModel;         // [t][64]
    bf16_t* Cb16  = Bb16 + (size_t)kM * kState;       // [t][64]
    bf16_t* xdtT  = Cb16 + (size_t)kM * kState;       // [(b,c,h)][64][256]
    bf16_t* bTg   = xdtT + (size_t)kM * kDModel;      // [(b,c)][64][256]
    bf16_t* wcat  = bTg + (size_t)kBatch * kNChunk * kState * kChunk;    // [192][2048]
    bf16_t* wob   = wcat + (size_t)192 * kDModel;     // bf16 out_w, slot-major

    const dim3 blk(256);
    // packs: out_w (2048) | BCdt padded to 192 rows (1536)
    prep_fused<<<dim3(2048 + 1536), blk, 0, stream>>>(out_w, wob, B_w, C_w, dt_w, wcat);
    // B/C/dt projection: pipelined (counted vmcnt) from fp32 x, 256 blocks
    gemm_bcdt<<<dim3(kM / 32), blk, 0, stream>>>(x, wcat, B_b, C_b, dt_b,
                                                 Bb16, Cb16, dtm);
    // fused: dtcumsum (1024) | bT (32) | xdtT from fp32 x (1024)
    mid_fused<<<dim3(1024 + 32 + 1024), blk, 0, stream>>>(
        dtm, A_log, Acs, Bb16, bTg, x, xdtT);
    states_mfma<<<dim3(kBatch * kNChunk * kHeads), blk, 0, stream>>>(xdtT, bTg, Acs, states);
    chunkscan_kernel<<<dim3(kBatch * kHeads * 16), blk, 0, stream>>>(states, Acs, prevsb);
    ychunk_mfma<<<dim3(kBatch * kNChunk * kHeads * 4), blk, 0, stream>>>(
        Bb16, Cb16, xdtT, Acs, prevsb, dtm, Dvec, Y);
    gemm256_out<<<dim3(256), dim3(512), 0, stream>>>(Y, wob, out_b, out);
}